// Round 4
// baseline (1688.952 us; speedup 1.0000x reference)
//
#include <hip/hip_runtime.h>
#include <hip/hip_bf16.h>

#define TT 64
#define BB 4096
#define HH 256
#define BMb 16             // batches per block
#define NBLK (BB / BMb)    // 256 blocks -> 1 block/CU, 8 waves (2/SIMD)

typedef short bf16x8_t __attribute__((ext_vector_type(8)));
typedef float f32x4_t  __attribute__((ext_vector_type(4)));

// d_ws layout (byte offsets)
#define WS_WA_B   0u          // split bf16 weights: 2 layers*3 parts*8kt*16nt*64lane*8j shorts = 768 KB
#define WS_EMB_B  786432u     // emb f32
#define WS_REC_B  1048576u    // rec f32 [T][B][4], 4 MB

__device__ __forceinline__ float clip01f(float v) {
    return fminf(fmaxf(v, 0.0f), 1.0f);
}

__global__ __launch_bounds__(64) void setup_emb_kernel(float* __restrict__ emb) {
    int i = threadIdx.x;
    const double sigma = 64.0 / 10.0;
    const double c = 32.0;
    double d = ((double)i - c) / sigma;
    double e = exp(-0.5 * (d * d));
    double d0 = (0.0 - c) / sigma;
    double emin = exp(-0.5 * (d0 * d0));
    emb[i] = (float)((e - emin) / (1.0 - emin));
}

// Exact 3-way split w = hi + mid + lo into bf16 parts (residuals exact).
// Pre-swizzled to A-fragment order for mfma_f32_16x16x32_bf16:
// A[m=lane&15][k=(lane>>4)*8+j], flat = ((((layer*3+part)*8+kt)*16+ntile)*64+lane)*8+j
__global__ __launch_bounds__(256) void split_weights_kernel(
    const float* __restrict__ W_h, const float* __restrict__ W_h2,
    unsigned short* __restrict__ WA)
{
    int flat = blockIdx.x * 256 + threadIdx.x;     // < 393216
    int j     = flat & 7;
    int lane  = (flat >> 3) & 63;
    int ntile = (flat >> 9) & 15;
    int kt    = (flat >> 13) & 7;
    int rest  = flat >> 16;                        // 0..5
    int part  = rest % 3;
    int layer = rest / 3;
    int k = kt * 32 + (lane >> 4) * 8 + j;
    int n = ntile * 16 + (lane & 15);
    const float* W = layer ? W_h2 : W_h;           // row-major [n][k] = W[n*256+k]
    float w = W[n * HH + k];
    __hip_bfloat16 h = __float2bfloat16(w);
    float r1 = w - __bfloat162float(h);
    __hip_bfloat16 m = __float2bfloat16(r1);
    float r2 = r1 - __bfloat162float(m);
    __hip_bfloat16 l = __float2bfloat16(r2);
    __hip_bfloat16 v = (part == 0) ? h : ((part == 1) ? m : l);
    WA[flat] = *reinterpret_cast<unsigned short*>(&v);
}

union U16x8 { uint4 u; bf16x8_t v; };

// ---- 512-thread / 8-wave structure: wave w owns n-tiles {2w, 2w+1}. ----
// VGPR budget escape: with 62KB static LDS, max 2 blocks/CU; at 512 thr that is
// 16 waves/CU = 4 waves/EU -> backend VGPR budget 128 (vs 64 with 1024-thr blocks,
// which spilled the prefetch slots to scratch in R1-R3: +184MB writes, L2 thrash,
// 5.7GB HBM fetch). Latency hiding moves from TLP to ILP: depth-2 rolling named-
// register prefetch x 2 tiles = 12 uint4 slots (48 VGPRs), ~6KB in flight per wave.
//
// STEP2: consume slot-group (both tiles, parts 0,1,2 in order -> per-D accumulation
// order IDENTICAL to baseline -> bit-identical D), then refill the group with data
// for kt+2 (or the next phase's kt0/kt1 at steps 6/7).
#define STEP2(A0, A1, A2, B0, B1, B2, Wr0, Wr1, ktr, Bp, ktb, D0, D1) do {     \
    U16x8 br_; br_.u = (Bp)[(ktb) * 64];            /* ds_read_b128 spikes */  \
    U16x8 x0_, x1_, x2_, y0_, y1_, y2_;                                        \
    x0_.u = A0; x1_.u = A1; x2_.u = A2;                                        \
    y0_.u = B0; y1_.u = B1; y2_.u = B2;                                        \
    D0 = __builtin_amdgcn_mfma_f32_16x16x32_bf16(x0_.v, br_.v, D0, 0, 0, 0);   \
    D0 = __builtin_amdgcn_mfma_f32_16x16x32_bf16(x1_.v, br_.v, D0, 0, 0, 0);   \
    D0 = __builtin_amdgcn_mfma_f32_16x16x32_bf16(x2_.v, br_.v, D0, 0, 0, 0);   \
    D1 = __builtin_amdgcn_mfma_f32_16x16x32_bf16(y0_.v, br_.v, D1, 0, 0, 0);   \
    D1 = __builtin_amdgcn_mfma_f32_16x16x32_bf16(y1_.v, br_.v, D1, 0, 0, 0);   \
    D1 = __builtin_amdgcn_mfma_f32_16x16x32_bf16(y2_.v, br_.v, D1, 0, 0, 0);   \
    A0 = (Wr0)[(0 * 8 + (ktr)) * 1024];                                        \
    A1 = (Wr0)[(1 * 8 + (ktr)) * 1024];                                        \
    A2 = (Wr0)[(2 * 8 + (ktr)) * 1024];                                        \
    B0 = (Wr1)[(0 * 8 + (ktr)) * 1024];                                        \
    B1 = (Wr1)[(1 * 8 + (ktr)) * 1024];                                        \
    B2 = (Wr1)[(2 * 8 + (ktr)) * 1024];                                        \
} while (0)

// kt = 0..7 ascending; enters with g0=kt0, g1=kt1 (issued >=2 steps earlier);
// steps 0..5 refill kt+2, steps 6..7 refill NEXT phase's kt0/kt1.
#define MFMA_PHASE2(Wc0, Wc1, Wn0, Wn1, Bp, D0, D1) do {                       \
    STEP2(g0t0a, g0t0b, g0t0c, g0t1a, g0t1b, g0t1c, Wc0, Wc1, 2, Bp, 0, D0, D1); \
    STEP2(g1t0a, g1t0b, g1t0c, g1t1a, g1t1b, g1t1c, Wc0, Wc1, 3, Bp, 1, D0, D1); \
    STEP2(g0t0a, g0t0b, g0t0c, g0t1a, g0t1b, g0t1c, Wc0, Wc1, 4, Bp, 2, D0, D1); \
    STEP2(g1t0a, g1t0b, g1t0c, g1t1a, g1t1b, g1t1c, Wc0, Wc1, 5, Bp, 3, D0, D1); \
    STEP2(g0t0a, g0t0b, g0t0c, g0t1a, g0t1b, g0t1c, Wc0, Wc1, 6, Bp, 4, D0, D1); \
    STEP2(g1t0a, g1t0b, g1t0c, g1t1a, g1t1b, g1t1c, Wc0, Wc1, 7, Bp, 5, D0, D1); \
    STEP2(g0t0a, g0t0b, g0t0c, g0t1a, g0t1b, g0t1c, Wn0, Wn1, 0, Bp, 6, D0, D1); \
    STEP2(g1t0a, g1t0b, g1t0c, g1t1a, g1t1b, g1t1c, Wn0, Wn1, 1, Bp, 7, D0, D1); \
} while (0)

// Fill g0 with kt0, g1 with kt1 (parts 0..2, both tiles): slot = W[(part*8+kt)*1024]
#define PREFILL2(Wt0, Wt1) do {                                                \
    g0t0a = (Wt0)[ 0 * 1024]; g0t0b = (Wt0)[ 8 * 1024]; g0t0c = (Wt0)[16 * 1024]; \
    g0t1a = (Wt1)[ 0 * 1024]; g0t1b = (Wt1)[ 8 * 1024]; g0t1c = (Wt1)[16 * 1024]; \
    g1t0a = (Wt0)[ 1 * 1024]; g1t0b = (Wt0)[ 9 * 1024]; g1t0c = (Wt0)[17 * 1024]; \
    g1t1a = (Wt1)[ 1 * 1024]; g1t1b = (Wt1)[ 9 * 1024]; g1t1c = (Wt1)[17 * 1024]; \
} while (0)

// li_out walker for timestep t (wave 0 only). Ascending-k fmaf chain over
// S3F spikes (0.0/1.0): fmaf(1,w,p)=round(p+w), fmaf(0,w,p)=p -> bit-identical
// to the baseline select-add chain ("skip-zero == exact chain").
__device__ __forceinline__ void li_walker(
    const float* __restrict__ WoutS, const float (*__restrict__ S3F)[260],
    int wb, int ooc, float bto, float bo, float& m3s,
    float* __restrict__ rec, int t, int b0, int lane)
{
    if (lane < 32) {
        const float* wrow = WoutS + ooc * HH;
        const float* srow = S3F[wb];
        float p = 0.f;
#pragma unroll 8
        for (int k4 = 0; k4 < 64; ++k4) {
            float4 sv = *(const float4*)(srow + k4 * 4);
            float4 wv = *(const float4*)(wrow + k4 * 4);
            p = fmaf(sv.x, wv.x, p);
            p = fmaf(sv.y, wv.y, p);
            p = fmaf(sv.z, wv.z, p);
            p = fmaf(sv.w, wv.w, p);
        }
        float mm3 = fmaf(bto, m3s, p);
        mm3 = mm3 + bo;
        m3s = mm3;
        float spk = ((m3s - 1.0f) > 0.f) ? 1.f : 0.f;
        float om3 = __shfl_xor(m3s, 16, 64);
        float osp = __shfl_xor(spk, 16, 64);
        if (lane < 16) {
            *(float4*)(rec + ((size_t)t * BB + b0 + wb) * 4) =
                make_float4(spk, osp, m3s, om3);
        }
    }
}

__global__ __launch_bounds__(512) void snn_main_kernel(
    const float* __restrict__ x,
    const float* __restrict__ W_in, const float* __restrict__ b_in,
    const float* __restrict__ beta_in, const float* __restrict__ thr_in,
    const float* __restrict__ b_h, const float* __restrict__ beta_h, const float* __restrict__ thr_h,
    const float* __restrict__ b_h2, const float* __restrict__ beta_h2, const float* __restrict__ thr_h2,
    const float* __restrict__ W_out, const float* __restrict__ b_out, const float* __restrict__ beta_out,
    const unsigned short* __restrict__ WA, const float* __restrict__ emb,
    float* __restrict__ rec)
{
#pragma clang fp contract(off)   // all contraction EXPLICIT via fmaf
    const int tid = threadIdx.x;
    const int w = tid >> 6;       // wave 0..7: owns n-tiles 2w, 2w+1
    const int lane = tid & 63;
    const int b = lane & 15;      // batch column (D col = lane&15)
    const int g = lane >> 4;      // row group   (D row = g*4+reg)
    const int b0 = blockIdx.x * BMb;

    __shared__ unsigned short sbuf1[8 * 64 * 8];            // B-frags spikes layer1 (8 KB)
    __shared__ unsigned short sbuf2[8 * 64 * 8];            // B-frags spikes layer2 (8 KB)
    __shared__ __align__(16) float S3F[16][260];            // layer-3 spikes [batch][n]
    __shared__ __align__(16) float WoutS[2 * HH];
    __shared__ float4 PL1a[HH];   // {wi0, wi1, wi2, b_in}
    __shared__ float2 PL1b[HH];   // {bt1c, th1}
    __shared__ float4 PL2[HH];    // {b_h,  bt2c, th2, -}
    __shared__ float4 PL3[HH];    // {b_h2, bt3c, th3, -}
    __shared__ float  xs[TT][BMb][3];   // staged x slice (12 KB)
    __shared__ float  embS[TT];

    WoutS[tid] = W_out[tid];      // 512 threads = 512 elems
    if (tid < HH) {
        int n = tid;
        PL1a[n] = make_float4(W_in[n * 3], W_in[n * 3 + 1], W_in[n * 3 + 2], b_in[n]);
        PL1b[n] = make_float2(clip01f(beta_in[n]), thr_in[n]);
        PL2[n]  = make_float4(b_h[n],  clip01f(beta_h[n]),  thr_h[n],  0.f);
        PL3[n]  = make_float4(b_h2[n], clip01f(beta_h2[n]), thr_h2[n], 0.f);
    }
    if (tid < TT) embS[tid] = emb[tid];
#pragma unroll
    for (int i = tid; i < TT * BMb; i += 512) {   // 2 iters: 64 t * 16 batches
        int ts = i >> 4, bb = i & 15;
        const float* xp = x + ((size_t)ts * BB + b0 + bb) * 3;
        xs[ts][bb][0] = xp[0];
        xs[ts][bb][1] = xp[1];
        xs[ts][bb][2] = xp[2];
    }

    // this thread's 8 neurons: n = (2w+u)*16 + g*4 + r, u in {0,1}
    const int nb0 = w * 32 + g * 4;

    float m1[2][4], m2[2][4], m4[2][4];
#pragma unroll
    for (int u = 0; u < 2; ++u)
#pragma unroll
        for (int r = 0; r < 4; ++r) { m1[u][r] = 0.f; m2[u][r] = 0.f; m4[u][r] = 0.f; }

    // spike -> B-frag LDS address for tile nt=2w+u (one b64 per thread per tile):
    // k=n: kt2 = nt>>1 = w, q = (nt&1)*2 + (g>>1), dst_lane = q*16+b, j0 = (g&1)*4
    // u=0 at sb0, u=1 at sb0+256 (q += 2 -> +32 lanes * 8 shorts)
    const int sb0 = ((w * 64 + ((g >> 1) * 16 + b)) * 8 + (g & 1) * 4);

    // li_out walker state (wave 0, lanes 0..31): wb = batch, ooc = channel
    const int wb = lane & 15;
    const int ooc = (lane >> 4) & 1;
    float bto = clip01f(beta_out[ooc]);
    float bo = b_out[ooc];
    float m3s = 0.f;

    // A-fragment bases, pre-offset by this thread's (tile, lane); uint4 units.
    // flat idx = ((layer*3+part)*8+kt)*16 + ntile)*64 + lane; layer stride = 24576.
    const uint4* W00 = (const uint4*)WA + (size_t)(2 * w) * 64 + lane;  // layer2 tile0
    const uint4* W01 = W00 + 64;                                        // layer2 tile1
    const uint4* W10 = W00 + 24576;                                     // layer3 tile0
    const uint4* W11 = W01 + 24576;                                     // layer3 tile1
    const uint4* Bp1 = (const uint4*)sbuf1 + lane;
    const uint4* Bp2 = (const uint4*)sbuf2 + lane;

    // 12 NAMED prefetch slots (48 VGPRs): groups g0 (even kt), g1 (odd kt),
    // each = {tile0, tile1} x {part0,1,2}
    uint4 g0t0a, g0t0b, g0t0c, g0t1a, g0t1b, g0t1c;
    uint4 g1t0a, g1t0b, g1t0c, g1t1a, g1t1b, g1t1c;
    PREFILL2(W00, W01);           // t=0 layer-2 kt0,kt1 in flight before the loop

    __syncthreads();              // LDS init visible; prefill drains free here

    for (int t = 0; t < TT; ++t) {
        // ---- phase A: layer 1, exact f32 chain + contracted LIF; spikes -> B-frag LDS ----
        {
            float et = embS[t];
            float xe0 = xs[t][b][0] * et;
            float xe1 = xs[t][b][1] * et;
            float xe2 = xs[t][b][2] * et;
            unsigned sp[2][4];
#pragma unroll
            for (int u = 0; u < 2; ++u)
#pragma unroll
            for (int r = 0; r < 4; ++r) {
                int n = nb0 + u * 16 + r;
                float4 pa = PL1a[n];
                float2 pb = PL1b[n];
                float a1 = xe0 * pa.x;
                a1 = fmaf(xe1, pa.y, a1);
                a1 = fmaf(xe2, pa.z, a1);
                float cur = a1 + pa.w;
                float rf = ((m1[u][r] - pb.y) > 0.f) ? 1.f : 0.f;  // reset from PREVIOUS mem
                float mm = fmaf(pb.x, m1[u][r], cur);              // contracted: beta*m + cur
                mm = fmaf(-rf, pb.y, mm);                          // contracted: - reset*thr
                m1[u][r] = mm;
                sp[u][r] = ((mm - pb.y) > 0.f) ? 0x3F80u : 0u;     // bf16 1.0 / 0.0
            }
            *(uint2*)(sbuf1 + sb0)       = make_uint2(sp[0][0] | (sp[0][1] << 16), sp[0][2] | (sp[0][3] << 16));
            *(uint2*)(sbuf1 + sb0 + 256) = make_uint2(sp[1][0] | (sp[1][1] << 16), sp[1][2] | (sp[1][3] << 16));
        }
        __syncthreads();   // BAR1

        // ---- phase B: wave0 runs walker(t-1) first (hides under others' MFMA/VMEM);
        //      then layer-2 MFMA (2 tiles) with named-reg prefetched A; epilogue LIF ----
        if (w == 0 && t > 0)
            li_walker(WoutS, S3F, wb, ooc, bto, bo, m3s, rec, t - 1, b0, lane);
        {
            f32x4_t D0 = (f32x4_t){0.f, 0.f, 0.f, 0.f};
            f32x4_t D1 = (f32x4_t){0.f, 0.f, 0.f, 0.f};
            MFMA_PHASE2(W00, W01, W10, W11, Bp1, D0, D1);  // exits with slots = layer-3 kt0,kt1
            unsigned sp[2][4];
#pragma unroll
            for (int r = 0; r < 4; ++r) {
                int n0 = nb0 + r;
                float4 p2 = PL2[n0];
                float cur = D0[r] + p2.x;
                float rf = ((m2[0][r] - p2.z) > 0.f) ? 1.f : 0.f;
                float mm = fmaf(p2.y, m2[0][r], cur);
                mm = fmaf(-rf, p2.z, mm);
                m2[0][r] = mm;
                sp[0][r] = ((mm - p2.z) > 0.f) ? 0x3F80u : 0u;
            }
#pragma unroll
            for (int r = 0; r < 4; ++r) {
                int n1 = nb0 + 16 + r;
                float4 p2 = PL2[n1];
                float cur = D1[r] + p2.x;
                float rf = ((m2[1][r] - p2.z) > 0.f) ? 1.f : 0.f;
                float mm = fmaf(p2.y, m2[1][r], cur);
                mm = fmaf(-rf, p2.z, mm);
                m2[1][r] = mm;
                sp[1][r] = ((mm - p2.z) > 0.f) ? 0x3F80u : 0u;
            }
            *(uint2*)(sbuf2 + sb0)       = make_uint2(sp[0][0] | (sp[0][1] << 16), sp[0][2] | (sp[0][3] << 16));
            *(uint2*)(sbuf2 + sb0 + 256) = make_uint2(sp[1][0] | (sp[1][1] << 16), sp[1][2] | (sp[1][3] << 16));
        }
        __syncthreads();   // BAR2 (also fences walker's S3F reads vs next writes)

        // ---- phase C: layer-3 MFMA (2 tiles); epilogue LIF -> S3F spike floats ----
        {
            f32x4_t E0 = (f32x4_t){0.f, 0.f, 0.f, 0.f};
            f32x4_t E1 = (f32x4_t){0.f, 0.f, 0.f, 0.f};
            MFMA_PHASE2(W10, W11, W00, W01, Bp2, E0, E1);  // exits with slots = next-t layer-2 kt0,kt1
            float s3v[2][4];
#pragma unroll
            for (int r = 0; r < 4; ++r) {
                int n0 = nb0 + r;
                float4 p3 = PL3[n0];
                float cur = E0[r] + p3.x;
                float rf = ((m4[0][r] - p3.z) > 0.f) ? 1.f : 0.f;
                float mm = fmaf(p3.y, m4[0][r], cur);
                mm = fmaf(-rf, p3.z, mm);
                m4[0][r] = mm;
                s3v[0][r] = ((mm - p3.z) > 0.f) ? 1.0f : 0.0f;
            }
#pragma unroll
            for (int r = 0; r < 4; ++r) {
                int n1 = nb0 + 16 + r;
                float4 p3 = PL3[n1];
                float cur = E1[r] + p3.x;
                float rf = ((m4[1][r] - p3.z) > 0.f) ? 1.f : 0.f;
                float mm = fmaf(p3.y, m4[1][r], cur);
                mm = fmaf(-rf, p3.z, mm);
                m4[1][r] = mm;
                s3v[1][r] = ((mm - p3.z) > 0.f) ? 1.0f : 0.0f;
            }
            *(float4*)(&S3F[b][nb0])      = make_float4(s3v[0][0], s3v[0][1], s3v[0][2], s3v[0][3]);
            *(float4*)(&S3F[b][nb0 + 16]) = make_float4(s3v[1][0], s3v[1][1], s3v[1][2], s3v[1][3]);
        }
        __syncthreads();   // BAR3
    }

    // final walker for t = 63
    if (w == 0)
        li_walker(WoutS, S3F, wb, ooc, bto, bo, m3s, rec, TT - 1, b0, lane);
}

// out[r,o] = (ascending-k fma dot) + b_pred[o]
__global__ __launch_bounds__(256) void pred_kernel(
    const float* __restrict__ rec, const float* __restrict__ W_pred,
    const float* __restrict__ b_pred, float* __restrict__ out)
{
#pragma clang fp contract(off)
    int r = blockIdx.x * 256 + threadIdx.x;   // 0..4095
    const float* f = rec + (size_t)r * 256;
    float a0 = 0.f, a1 = 0.f;
#pragma unroll 4
    for (int c = 0; c < 256; ++c) {
        float v = f[c];
        a0 = fmaf(v, W_pred[c], a0);
        a1 = fmaf(v, W_pred[256 + c], a1);
    }
    out[r * 2 + 0] = a0 + b_pred[0];
    out[r * 2 + 1] = a1 + b_pred[1];
}

extern "C" void kernel_launch(void* const* d_in, const int* in_sizes, int n_in,
                              void* d_out, int out_size, void* d_ws, size_t ws_size,
                              hipStream_t stream)
{
    const float* x        = (const float*)d_in[0];
    const float* W_in     = (const float*)d_in[1];
    const float* b_in     = (const float*)d_in[2];
    const float* beta_in  = (const float*)d_in[3];
    const float* thr_in   = (const float*)d_in[4];
    const float* W_h      = (const float*)d_in[5];
    const float* b_h      = (const float*)d_in[6];
    const float* beta_h   = (const float*)d_in[7];
    const float* thr_h    = (const float*)d_in[8];
    const float* W_h2     = (const float*)d_in[9];
    const float* b_h2     = (const float*)d_in[10];
    const float* beta_h2  = (const float*)d_in[11];
    const float* thr_h2   = (const float*)d_in[12];
    const float* W_out    = (const float*)d_in[13];
    const float* b_out    = (const float*)d_in[14];
    const float* beta_out = (const float*)d_in[15];
    const float* W_pred   = (const float*)d_in[16];
    const float* b_pred   = (const float*)d_in[17];

    char* ws = (char*)d_ws;
    unsigned short* WA = (unsigned short*)(ws + WS_WA_B);
    float* emb = (float*)(ws + WS_EMB_B);
    float* rec = (float*)(ws + WS_REC_B);

    split_weights_kernel<<<1536, 256, 0, stream>>>(W_h, W_h2, WA);
    setup_emb_kernel<<<1, 64, 0, stream>>>(emb);

    snn_main_kernel<<<NBLK, 512, 0, stream>>>(
        x, W_in, b_in, beta_in, thr_in,
        b_h, beta_h, thr_h,
        b_h2, beta_h2, thr_h2,
        W_out, b_out, beta_out,
        WA, emb, rec);

    pred_kernel<<<BB / 256, 256, 0, stream>>>(rec, W_pred, b_pred, (float*)d_out);
}